// Round 7
// baseline (236.479 us; speedup 1.0000x reference)
//
#include <hip/hip_runtime.h>

#define T_STEPS 512
#define BATCH   2048
#define HID     64
#define IN0     8
#define SPW     16                // distinct seqs per block (MFMA N dim)
#define NBLK    (BATCH / SPW)     // 128 blocks x 8 waves (512 thr)
#define SS      8                 // x-prefetch depth
#define NSS     (T_STEPS / SS)

typedef _Float16 h2 __attribute__((ext_vector_type(2)));
typedef _Float16 h4 __attribute__((ext_vector_type(4)));
typedef _Float16 h8 __attribute__((ext_vector_type(8)));
typedef float    f4 __attribute__((ext_vector_type(4)));

#define MFMA(a, b, c) __builtin_amdgcn_mfma_f32_16x16x32_f16((a), (b), (c), 0, 0, 0)

union F8 { h8 v; h2 p[4]; };
union H4U { h4 v; h2 p[2]; };

__device__ __forceinline__ h2 pkrtz(float a, float b) {
    return __builtin_bit_cast(h2, __builtin_amdgcn_cvt_pkrtz(a, b));
}

// tanh(x) = 1 - 2/(exp(2x)+1); saturates correctly at +/-inf.
__device__ __forceinline__ float tanh_fast(float x) {
    float e = __builtin_amdgcn_exp2f(x * 2.885390081777927f);
    return 1.0f - 2.0f * __builtin_amdgcn_rcpf(e + 1.0f);
}

__device__ __forceinline__ h8 load_frag_f16(const float* Wrow) {
    const float4* p = (const float4*)Wrow;
    float4 a = p[0], b = p[1];
    F8 f; f.p[0] = pkrtz(a.x, a.y); f.p[1] = pkrtz(a.z, a.w);
          f.p[2] = pkrtz(b.x, b.y); f.p[3] = pkrtz(b.z, b.w);
    return f.v;
}

// Barrier draining ONLY lgkmcnt (LDS); x-prefetch globals stay in flight.
// The lgkmcnt(0) also guarantees pre-barrier LDS reads complete before any
// wave passes the barrier and overwrites the slot they read (lag-safety).
#define LDS_BARRIER() asm volatile("s_waitcnt lgkmcnt(0)\n\ts_barrier" ::: "memory")

// H exchange layout: h8 H[bf][p][n], p=0..7, n=0..15 (2 KB per tile per bf).
//   element [p][n] = rows 8p..8p+7 of H (one full B-fragment k-slice).
//   read frag kt, lane (q,n):  H[bf][4kt+q][n]     -> 1x ds_read_b128,
//       banks 4(n%8)..+3, n vs n+8 alias = 2-way (free, m136).
//   write wave mt, lane (q,n): h4 half (q&1) of H[bf][2mt+(q>>1)][n]
//       -> ds_write_b64, 2-way max (free). Conflict-free verified R5-style.
__global__ __launch_bounds__(512, 1)
void rnn2_lag(const float* __restrict__ x,
              const float* __restrict__ Wih0, const float* __restrict__ Whh0,
              const float* __restrict__ bih0, const float* __restrict__ bhh0,
              const float* __restrict__ Wih1, const float* __restrict__ Whh1,
              const float* __restrict__ bih1, const float* __restrict__ bhh1,
              const float* __restrict__ fcw,  const float* __restrict__ fcb,
              float* __restrict__ out) {
    const int tid  = threadIdx.x;
    const int w    = tid >> 6;
    const int mt   = w & 3;        // m-tile (H rows 16mt..16mt+15)
    const bool L0  = (w < 4);      // waves 0-3: layer0; waves 4-7: layer1
    const int lane = tid & 63;
    const int n    = lane & 15;    // B/C column = sequence (16 distinct)
    const int q    = lane >> 4;
    const int bseq = blockIdx.x * SPW;

    __shared__ __align__(16) h8 H0p[2][8][16];   // 4 KB
    __shared__ __align__(16) h8 H1p[2][8][16];   // 4 KB
    __shared__ float red[4][SPW];

    const int wp  = 2 * mt + (q >> 1);   // write pair index
    const int ws  = q & 1;               // write sub-slot

    const f4 zero = {0.f, 0.f, 0.f, 0.f};
    const h2 z2 = pkrtz(0.f, 0.f);

    // ---- per-role weight fragments (slot j <-> k = 32kt+8q+j) ----
    h8 wa[2], wb[2], wi0;          // L0: wa=Whh0 | L1: wa=Wih1, wb=Whh1
    f4 biasc, fcv;
    const int row = 16 * mt + n;
    if (L0) {
        #pragma unroll
        for (int kt = 0; kt < 2; ++kt)
            wa[kt] = load_frag_f16(Whh0 + row * HID + 32 * kt + 8 * q);
        const float2 ww = *(const float2*)(Wih0 + row * IN0 + 2 * q);
        F8 f; f.p[0] = pkrtz(ww.x, ww.y); f.p[1] = z2; f.p[2] = z2; f.p[3] = z2;
        wi0 = f.v;
        #pragma unroll
        for (int r = 0; r < 4; ++r) {
            const int i = 16 * mt + 4 * q + r;
            biasc[r] = bih0[i] + bhh0[i];
        }
    } else {
        #pragma unroll
        for (int kt = 0; kt < 2; ++kt) {
            wa[kt] = load_frag_f16(Wih1 + row * HID + 32 * kt + 8 * q);
            wb[kt] = load_frag_f16(Whh1 + row * HID + 32 * kt + 8 * q);
        }
        #pragma unroll
        for (int r = 0; r < 4; ++r) {
            const int i = 16 * mt + 4 * q + r;
            biasc[r] = bih1[i] + bhh1[i];
            fcv[r]   = fcw[i];
        }
    }
    const float fcb0 = fcb[0];

    const float* xrow = x + ((size_t)(bseq + n) * T_STEPS) * IN0 + 2 * q;

    // L0 regs: h0f = B-frags of H0(t-1) (post-barrier read).
    // L1 regs: h0n = B-frags of H0(t-2) (PRE-barrier read, lag-2 feed),
    //          h1f = B-frags of H1(t-3) (post-barrier read).
    // L1 step t computes Y(t)=H1(t-2); t<2 publishes zeros (H1(-1)=0 init).
    h8 h0f[2] = {}, h0n[2] = {}, h1f[2] = {};
    f4 a0x;                        // L0: bias0 + Wih0@x(t), one step ahead
    float2 xb[SS];                 // rolling x prefetch (L0 only)
    if (L0) {
        const float2 x0 = *(const float2*)xrow;
        F8 xf; xf.p[0] = pkrtz(x0.x, x0.y); xf.p[1] = z2; xf.p[2] = z2; xf.p[3] = z2;
        a0x = MFMA(wi0, xf.v, biasc);
        #pragma unroll
        for (int i = 0; i < SS; ++i) {
            int tn = i + 1; if (tn > T_STEPS - 1) tn = T_STEPS - 1;
            xb[i] = *(const float2*)(xrow + tn * IN0);
        }
        __builtin_amdgcn_s_setprio(1);   // L0 = critical recurrence
    }

    for (int s = 0; s < NSS; ++s) {
        #pragma unroll
        for (int i = 0; i < SS; ++i) {
            const int t = SS * s + i;
            const int bf = t & 1;
            if (L0) {
                // H0(t) = tanh(a0x + Whh0@H0(t-1)); independent accumulators
                f4 p0 = MFMA(wa[0], h0f[0], a0x);
                f4 p1 = MFMA(wa[1], h0f[1], zero);
                const f4 a0 = p0 + p1;
                H4U u;
                u.p[0] = pkrtz(tanh_fast(a0[0]), tanh_fast(a0[1]));
                u.p[1] = pkrtz(tanh_fast(a0[2]), tanh_fast(a0[3]));
                ((h4*)&H0p[bf][wp][n])[ws] = u.v;
                __builtin_amdgcn_s_setprio(0);
                // a0x(t+1) — off the chain; rolling refill (7 steps to land)
                F8 xf; xf.p[0] = pkrtz(xb[i].x, xb[i].y);
                xf.p[1] = z2; xf.p[2] = z2; xf.p[3] = z2;
                a0x = MFMA(wi0, xf.v, biasc);
                int tn = t + 1 + SS; if (tn > T_STEPS - 1) tn = T_STEPS - 1;
                xb[i] = *(const float2*)(xrow + tn * IN0);
            } else {
                // Y(t) = H1(t-2) = tanh(b1 + Wih1@H0(t-2) + Whh1@H1(t-3))
                f4 c0 = MFMA(wa[0], h0n[0], biasc);
                f4 c1 = MFMA(wa[1], h0n[1], zero);
                f4 c2 = MFMA(wb[0], h1f[0], zero);
                f4 c3 = MFMA(wb[1], h1f[1], zero);
                const f4 a1 = (c0 + c1) + (c2 + c3);
                H4U u;
                u.p[0] = pkrtz(tanh_fast(a1[0]), tanh_fast(a1[1]));
                u.p[1] = pkrtz(tanh_fast(a1[2]), tanh_fast(a1[3]));
                if (t < 2) { u.p[0] = z2; u.p[1] = z2; }   // H1(-1)=0 init
                ((h4*)&H1p[bf][wp][n])[ws] = u.v;
                // PRE-barrier read: H0(t-1) from slot bf^1 (not written this
                // step; published at barrier t-1; lgkmcnt(0) before s_barrier
                // completes it before any wave can start overwriting).
                h0n[0] = H0p[bf ^ 1][q][n];
                h0n[1] = H0p[bf ^ 1][4 + q][n];
            }
            LDS_BARRIER();
            if (L0) {
                __builtin_amdgcn_s_setprio(1);
                h0f[0] = H0p[bf][q][n];
                h0f[1] = H0p[bf][4 + q][n];
            } else {
                h1f[0] = H1p[bf][q][n];
                h1f[1] = H1p[bf][4 + q][n];
            }
        }
    }

    // ---- epilogue ----
    // After step 511: h0n = H0(510), h1f = H1(509); H0(511) in H0p[1].
    // Step A: H1(510); step B: H1(511) -> FC head.
    if (!L0) {
        f4 e0 = MFMA(wa[0], h0n[0], biasc);
        f4 e1 = MFMA(wa[1], h0n[1], zero);
        f4 e2 = MFMA(wb[0], h1f[0], zero);
        f4 e3 = MFMA(wb[1], h1f[1], zero);
        const f4 aA = (e0 + e1) + (e2 + e3);      // H1(510) pre-tanh
        H4U u;
        u.p[0] = pkrtz(tanh_fast(aA[0]), tanh_fast(aA[1]));
        u.p[1] = pkrtz(tanh_fast(aA[2]), tanh_fast(aA[3]));
        ((h4*)&H1p[0][wp][n])[ws] = u.v;
    } else {
        __builtin_amdgcn_s_setprio(0);
    }
    LDS_BARRIER();
    if (!L0) {
        const h8 hx0 = H0p[1][q][n],  hx1 = H0p[1][4 + q][n];   // H0(511)
        const h8 g0  = H1p[0][q][n],  g1  = H1p[0][4 + q][n];   // H1(510)
        f4 f0 = MFMA(wa[0], hx0, biasc);
        f4 f1 = MFMA(wa[1], hx1, zero);
        f4 f2 = MFMA(wb[0], g0, zero);
        f4 f3 = MFMA(wb[1], g1, zero);
        const f4 a1 = (f0 + f1) + (f2 + f3);      // H1(511) pre-tanh
        float sacc = 0.f;
        #pragma unroll
        for (int r = 0; r < 4; ++r) sacc += fcv[r] * tanh_fast(a1[r]);
        sacc += __shfl_xor(sacc, 16, 64);
        sacc += __shfl_xor(sacc, 32, 64);
        if (lane < 16) red[mt][n] = sacc;    // q==0 lanes
    }
    __syncthreads();
    if (tid < SPW)
        out[bseq + tid] = red[0][tid] + red[1][tid] + red[2][tid] + red[3][tid] + fcb0;
}

extern "C" void kernel_launch(void* const* d_in, const int* in_sizes, int n_in,
                              void* d_out, int out_size, void* d_ws, size_t ws_size,
                              hipStream_t stream) {
    const float* x    = (const float*)d_in[0];
    const float* Wih0 = (const float*)d_in[1];
    const float* Whh0 = (const float*)d_in[2];
    const float* bih0 = (const float*)d_in[3];
    const float* bhh0 = (const float*)d_in[4];
    const float* Wih1 = (const float*)d_in[5];
    const float* Whh1 = (const float*)d_in[6];
    const float* bih1 = (const float*)d_in[7];
    const float* bhh1 = (const float*)d_in[8];
    const float* fcw  = (const float*)d_in[9];
    const float* fcb  = (const float*)d_in[10];
    float* out = (float*)d_out;

    rnn2_lag<<<dim3(NBLK), dim3(512), 0, stream>>>(
        x, Wih0, Whh0, bih0, bhh0, Wih1, Whh1, bih1, bhh1, fcw, fcb, out);
}